// Round 13
// baseline (798.103 us; speedup 1.0000x reference)
//
#include <hip/hip_runtime.h>
#include <hip/hip_bf16.h>

typedef short bf16x8 __attribute__((ext_vector_type(8)));
typedef float f32x16 __attribute__((ext_vector_type(16)));
typedef unsigned short u16;

__device__ __forceinline__ u16 f2bf(float v) {
    union { __hip_bfloat16 h; u16 u; } cv;
    cv.h = __float2bfloat16(v);
    return cv.u;
}

__device__ __forceinline__ void gld_lds16(const u16* g, u16* l) {
    __builtin_amdgcn_global_load_lds(
        (const __attribute__((address_space(1))) void*)g,
        (__attribute__((address_space(3))) void*)l, 16, 0, 0);
}

// ---------------- prep kernels ----------------
// Wt layout: [T][ocs(8)][c(4)][ocl(64)][e(8)]  with T = (ic>>5)*TAPS + tap
__global__ void prep_w1(const float* __restrict__ w, u16* __restrict__ o) {
    int idx = blockIdx.x * 256 + threadIdx.x;
    if (idx >= 25 * 512 * 512) return;
    int e = idx & 7, ocl = (idx >> 3) & 63, c = (idx >> 9) & 3;
    int ocs = (idx >> 11) & 7, T = idx >> 14;
    int icb = T / 25, tap = T - icb * 25;
    int ic = icb * 32 + c * 8 + e;
    int oc = ocs * 64 + ocl;
    int kh = tap / 5, kw = tap - kh * 5;
    o[idx] = f2bf(w[(((size_t)oc * 512 + ic) * 5 + kh) * 5 + kw]);
}

__global__ void prep_w2(const float* __restrict__ w, u16* __restrict__ o) {
    int idx = blockIdx.x * 256 + threadIdx.x;
    if (idx >= 15 * 512 * 512) return;
    int e = idx & 7, ocl = (idx >> 3) & 63, c = (idx >> 9) & 3;
    int ocs = (idx >> 11) & 7, T = idx >> 14;
    int icb = T / 15, tap = T - icb * 15;
    int ic = icb * 32 + c * 8 + e;
    int oc = ocs * 64 + ocl;
    int kh = tap / 3, kw = tap - kh * 3;
    o[idx] = f2bf(w[(((size_t)oc * 512 + ic) * 5 + kh) * 3 + kw]);
}

__global__ void prep_bn(const float* __restrict__ g, const float* __restrict__ b,
                        const float* __restrict__ m, const float* __restrict__ v,
                        float* __restrict__ scale, float* __restrict__ shift) {
    int i = blockIdx.x * 256 + threadIdx.x;
    if (i >= 512) return;
    float s = g[i] * rsqrtf(v[i] + 1e-5f);
    scale[i] = s;
    shift[i] = b[i] - m[i] * s;
}

// zero pads: gathered [b][cc64][row 12336][8] rows h in {0,1,1026,1027} (x12 w)
//            pooled1  [b][cc64][row 2064][8] rows hp in {0,1,514,515} (x4 w)
__global__ void zero_pads(u16* __restrict__ gath, u16* __restrict__ pooled) {
    int idx = blockIdx.x * 256 + threadIdx.x;
    if (idx < 24576) {
        int w = idx % 12, r = idx / 12;
        int h4 = r & 3; r >>= 2;
        int cc = r & 63, b = r >> 6;
        int h = (h4 < 2) ? h4 : 1024 + h4;        // 0,1,1026,1027
        *(int4*)&gath[(((size_t)(b * 64 + cc)) * 12336 + h * 12 + w) * 8] =
            int4{0, 0, 0, 0};
    } else if (idx < 24576 + 8192) {
        int j = idx - 24576;
        int w = j & 3, r = j >> 2;
        int h4 = r & 3; r >>= 2;
        int cc = r & 63, b = r >> 6;
        int hp = (h4 < 2) ? h4 : 512 + h4;        // 0,1,514,515
        *(int4*)&pooled[(((size_t)(b * 64 + cc)) * 2064 + hp * 4 + w) * 8] =
            int4{0, 0, 0, 0};
    }
}

// ---------------- scores + top-k + gather ----------------
// writes gathered[b][cc(64)][row = (t+2)*12 + s][8 ic] bf16
__global__ __launch_bounds__(256) void gather_topk(const float* __restrict__ x,
                                                   u16* __restrict__ g) {
    int bt = blockIdx.x;
    int b = bt >> 10, t = bt & 1023;
    const float* xb = x + (size_t)b * 1024 * 512;
    const float* xt = xb + (size_t)t * 512;
    __shared__ float xts[512];
    __shared__ float sc[23];
    __shared__ int sel[12];
    int tid = threadIdx.x;
    for (int i = tid; i < 512; i += 256) xts[i] = xt[i];
    __syncthreads();
    int j0 = t - 11; if (j0 < 0) j0 = 0;
    int j1 = t + 11; if (j1 > 1023) j1 = 1023;
    int C = j1 - j0 + 1;                        // 12..23, always >= 12
    int wave = tid >> 6, lane = tid & 63;
    for (int c = wave; c < C; c += 4) {
        const float* xj = xb + (size_t)(j0 + c) * 512;
        double s = 0.0;
        #pragma unroll
        for (int e = 0; e < 8; ++e) {
            int d = lane * 8 + e;
            s += (double)xj[d] * (double)xts[d];
        }
        #pragma unroll
        for (int off = 32; off; off >>= 1) s += __shfl_xor(s, off, 64);
        if (lane == 0) sc[c] = (float)(s / 22.627416997969522);  // / sqrt(512)
    }
    __syncthreads();
    // wave-parallel top-12 select (stable: lower index wins ties)
    if (tid < 64) {
        bool selme = false;
        float v = (tid < C) ? sc[tid] : 0.f;
        if (tid < C) {
            int r = 0;
            #pragma unroll
            for (int k = 0; k < 23; ++k) {
                if (k < C) {
                    float u = sc[k];
                    r += (u > v) || (u == v && k < tid);
                }
            }
            selme = (r < 12);
        }
        unsigned long long m = __ballot(selme);
        if (selme) {
            int posn = __popcll(m & ((1ull << tid) - 1ull));
            sel[posn] = j0 + tid;               // ascending c == sorted ids
        }
    }
    __syncthreads();
    const size_t rowbase = (size_t)(t + 2) * 12;
    for (int i = tid; i < 768; i += 256) {           // 64 cc x 12 s blocks
        int cc = i / 12, s = i - cc * 12;
        const float* src = xb + (size_t)sel[s] * 512 + cc * 8;
        float4 f0 = *(const float4*)src;
        float4 f1 = *(const float4*)(src + 4);
        u16 pk[8] = {f2bf(f0.x), f2bf(f0.y), f2bf(f0.z), f2bf(f0.w),
                     f2bf(f1.x), f2bf(f1.y), f2bf(f1.z), f2bf(f1.w)};
        *(int4*)&g[(((size_t)(b * 64 + cc)) * 12336 + rowbase + s) * 8] =
            *(const int4*)pk;
    }
}

// ---------------- implicit-GEMM conv + bias + BN + ReLU + fused 2x2 pool ----
// A: [b][cc(64)][row(PLANE)][8] bf16, rows H-zero-padded by 2.
// Wt: [T][ocs(8)][c(4)][ocl(64)][8] bf16, T = icb32*TAPS + tap (body-linear).
// LDS: A-only. conv1: double-buffered chunks, boundary = vmcnt(2NF) + 1 bar.
//      conv2: single buffer (3 blocks/CU), boundary = bar + stage + drain.
// W: GLOBAL->VGPR, 2-body alternating register sets (wE/wO), distance 1.
//    Single-base addressing (NF==2): per-chunk cursor wch, per-body
//    compile-time offsets {0,256,1024,1280} shorts -> minimal addr VALU.
// A-frags: half-body software pipeline (afA/afB).
// MFMA 32x32x16; wave grid 2^LOG_WN in n; wave tile (MF32*32) x (NF*32).
// Epilogue fuses the 2x2 maxpool (quad lives in one lane's C regs).

#define STAGEA_BUF(BUF, CH) do {                                              \
    _Pragma("unroll 1")                                                       \
    for (int q_ = wv; q_ < 8 * JC; q_ += WAVES) {                             \
        int c8_ = q_ / JC, j_ = q_ - c8_ * JC;                                \
        const u16* p_ = gAh +                                                 \
            ((size_t)(((CH) * 8 + c8_) * PLANE) + j_ * 64) * 8;               \
        if (CLAMPA && p_ > gAmax) p_ = gAmax;                                 \
        gld_lds16(p_, &As_l[(BUF)][c8_ * SLAB + j_ * 512]);                   \
    }                                                                         \
  } while (0)

#define CBODY(BI, WUSE, WPRE) do {                                            \
    const int gh_ = (BI) / TAPS, t_ = (BI) - gh_ * TAPS;                      \
    const int kh2_ = t_ / KW;                                                 \
    const int toff_ = kh2_ * IN_W + (t_ - kh2_ * KW);                         \
    const u16* aR_ = aBufc + gh_ * 4 * SLAB;                                  \
    const u16* wS_ = wch + (size_t)(BI) * 16384;                              \
    WPRE[0] = *(const bf16x8*)(wS_);                                          \
    WPRE[1] = *(const bf16x8*)(wS_ + 256);                                    \
    WPRE[2] = *(const bf16x8*)(wS_ + 1024);                                   \
    WPRE[3] = *(const bf16x8*)(wS_ + 1280);                                   \
    _Pragma("unroll")                                                         \
    for (int mf = 0; mf < MF32; ++mf)                                         \
        afB[mf] = *(const bf16x8*)(aR_ + (toff_ + MFR * mf) * 8 + 2 * SLAB);  \
    __builtin_amdgcn_s_setprio(1);                                            \
    _Pragma("unroll")                                                         \
    for (int mf = 0; mf < MF32; ++mf)                                         \
        _Pragma("unroll")                                                     \
        for (int nf = 0; nf < 2; ++nf)                                        \
            acc[mf][nf] = __builtin_amdgcn_mfma_f32_32x32x16_bf16(            \
                afA[mf], WUSE[nf], acc[mf][nf], 0, 0, 0);                     \
    __builtin_amdgcn_s_setprio(0);                                            \
    if ((BI) + 1 < NB) {                                                      \
        const int bn2_ = (BI) + 1;                                            \
        const int ghn_ = bn2_ / TAPS, tn_ = bn2_ - ghn_ * TAPS;               \
        const int khn_ = tn_ / KW;                                            \
        const int toffn_ = khn_ * IN_W + (tn_ - khn_ * KW);                   \
        const u16* aRn_ = aBufc + ghn_ * 4 * SLAB;                            \
        _Pragma("unroll")                                                     \
        for (int mf = 0; mf < MF32; ++mf)                                     \
            afA[mf] = *(const bf16x8*)(aRn_ + (toffn_ + MFR * mf) * 8);       \
    }                                                                         \
    __builtin_amdgcn_s_setprio(1);                                            \
    _Pragma("unroll")                                                         \
    for (int mf = 0; mf < MF32; ++mf)                                         \
        _Pragma("unroll")                                                     \
        for (int nf = 0; nf < 2; ++nf)                                        \
            acc[mf][nf] = __builtin_amdgcn_mfma_f32_32x32x16_bf16(            \
                afB[mf], WUSE[2 + nf], acc[mf][nf], 0, 0, 0);                 \
    __builtin_amdgcn_s_setprio(0);                                            \
  } while (0)

template <int IN_W, int LOG_OW, int KH, int KW, int TH, int HTB, int MF32,
          int LOG_WN, int NF, int NTILES, int WAVES, int MINW, int ARP,
          int PLANE, int CPX, bool DBUF, bool POOL2E>
__global__ __launch_bounds__(WAVES * 64, MINW) void conv_fused(
    const u16* __restrict__ A, const u16* __restrict__ Wt,
    const float* __restrict__ bias, const float* __restrict__ bnsc,
    const float* __restrict__ bnsh, void* __restrict__ outp) {
    static_assert(NF == 2, "W addressing assumes NF==2");
    constexpr int OW = 1 << LOG_OW;
    constexpr int TAPS = KH * KW;
    constexpr int JC = ARP / 64;
    constexpr int MFR = (32 >> LOG_OW) * IN_W;   // A-row advance per mf
    constexpr int SLAB = ARP * 8 + 32;           // shorts; +64B pad per slab
    constexpr int NB = 2 * TAPS;                 // bodies per chunk (even)
    constexpr int NBUF = DBUF ? 2 : 1;
    constexpr bool CLAMPA = POOL2E;              // conv2 ARP rounds past plane
    __shared__ u16 As_l[NBUF][8 * SLAB];

    const int tid = threadIdx.x;
    const int bid = blockIdx.x;
    const int lb = (bid & 7) * CPX + (bid >> 3);   // XCD-chunked swizzle
    const int n0 = (lb % NTILES) * (512 / NTILES);
    const int mt = lb / NTILES;
    const int b = mt / HTB;
    const int h0 = (mt % HTB) * TH;

    const int lane = tid & 63;
    const int wv = tid >> 6;
    const int wn = wv & ((1 << LOG_WN) - 1);
    const int wm = wv >> LOG_WN;
    const int l31 = lane & 31, kgrp = lane >> 5;

    const int pos0 = wm * MF32 * 32 + l31;
    const int rowb0 = (pos0 >> LOG_OW) * IN_W + (pos0 & (OW - 1));
    const int aoffb = kgrp * SLAB + rowb0 * 8;

    // per-lane W base (body T=0): ocs = ocs_base + wn, c = kgrp, ocl = l31.
    // nf=1 is +256 shorts (ocl+32); k1 is +1024 shorts (c+2).
    const int ocs_base = (lb % NTILES) * (8 / NTILES);
    const u16* wlane = Wt + (size_t)(ocs_base + wn) * 2048
                       + kgrp * 512 + l31 * 8;

    const u16* gAh = A + (((size_t)b * 64) * PLANE + h0 * IN_W + lane) * 8;
    const u16* gAmax = A + (size_t)512 * PLANE * 8 - 8;   // 8b x 64cc slabs

    f32x16 acc[MF32][NF];
    #pragma unroll
    for (int i = 0; i < MF32; ++i)
        #pragma unroll
        for (int j = 0; j < NF; ++j)
            acc[i][j] = f32x16{0.f,0.f,0.f,0.f,0.f,0.f,0.f,0.f,
                               0.f,0.f,0.f,0.f,0.f,0.f,0.f,0.f};

    // prologue: A chunk 0 -> buf0 (DMA); W body 0 -> wE set
    STAGEA_BUF(0, 0);
    bf16x8 wE[4], wO[4];
    wE[0] = *(const bf16x8*)(wlane);
    wE[1] = *(const bf16x8*)(wlane + 256);
    wE[2] = *(const bf16x8*)(wlane + 1024);
    wE[3] = *(const bf16x8*)(wlane + 1280);
    asm volatile("s_waitcnt vmcnt(0)" ::: "memory");
    __builtin_amdgcn_s_barrier();

    const u16* wch = wlane + 16384;               // body 1 W base
    #pragma unroll 1
    for (int cn = 0; cn < 8; ++cn) {
        if (DBUF && cn < 7) STAGEA_BUF((cn + 1) & 1, cn + 1);
        const u16* aBufc = &As_l[DBUF ? (cn & 1) : 0][0] + aoffb;
        // chunk head: afA <- body 0 k0
        bf16x8 afA[MF32], afB[MF32];
        #pragma unroll
        for (int mf = 0; mf < MF32; ++mf)
            afA[mf] = *(const bf16x8*)(aBufc + MFR * mf * 8);
        #pragma unroll
        for (int bi = 0; bi < NB; ++bi) {
            if ((bi & 1) == 0) CBODY(bi, wE, wO);
            else              CBODY(bi, wO, wE);
        }
        wch += (size_t)NB * 16384;
        if (DBUF) {
            // own A-DMAs are older than the 4 in-flight W loads
            asm volatile("s_waitcnt vmcnt(4)" ::: "memory");
            __builtin_amdgcn_s_barrier();
        } else if (cn < 7) {
            __builtin_amdgcn_s_barrier();
            STAGEA_BUF(0, cn + 1);
            asm volatile("s_waitcnt vmcnt(0)" ::: "memory");
            __builtin_amdgcn_s_barrier();
        }
    }
    asm volatile("s_waitcnt vmcnt(0)" ::: "memory");

    // epilogue: y = relu(max4(conv)*sc + (bias*sc + sh)), fused 2x2 pool.
    // C/D 32x32: col = lane&31, row = (r&3) + 8*(r>>2) + 4*(lane>>5)
    #pragma unroll
    for (int nf = 0; nf < NF; ++nf) {
        const int oc = n0 + wn * (NF * 32) + nf * 32 + l31;
        const float scv = bnsc[oc], shv = bnsh[oc], bi2 = bias[oc];
        const float shh = fmaf(bi2, scv, shv);
        #pragma unroll
        for (int mf = 0; mf < MF32; ++mf) {
            #pragma unroll
            for (int q = 0; q < 4; ++q) {
                if (!POOL2E) {
                    // quad {r0,r0+1,r0+4,r0+5}: w-pair (+1 row) x h-pair (+8)
                    const int r0 = (q & 1) * 2 + (q >> 1) * 8;   // 0,2,8,10
                    float mx = fmaxf(
                        fmaxf(acc[mf][nf][r0], acc[mf][nf][r0 + 1]),
                        fmaxf(acc[mf][nf][r0 + 4], acc[mf][nf][r0 + 5]));
                    float v = fmaxf(fmaf(mx, scv, shh), 0.f);
                    const int row0 = (r0 & 3) + 8 * (r0 >> 2) + 4 * kgrp;
                    const int pos = wm * MF32 * 32 + mf * 32 + row0;
                    const int h = h0 + (pos >> LOG_OW);
                    const int w = pos & (OW - 1);
                    const int prow = (2 + (h >> 1)) * 4 + (w >> 1);
                    u16* o = (u16*)outp;
                    o[(((size_t)(b * 64 + (oc >> 3))) * 2064 + prow) * 8 +
                      (oc & 7)] = f2bf(v);
                } else {
                    // quad {r0..r0+3}: 4 consecutive positions (h-pair x w-pair)
                    const int r0 = q * 4;
                    float mx = fmaxf(
                        fmaxf(acc[mf][nf][r0], acc[mf][nf][r0 + 1]),
                        fmaxf(acc[mf][nf][r0 + 2], acc[mf][nf][r0 + 3]));
                    float v = fmaxf(fmaf(mx, scv, shh), 0.f);
                    const int row0 = 8 * (r0 >> 2) + 4 * kgrp;
                    const int pos = wm * MF32 * 32 + mf * 32 + row0;
                    const int pout = (h0 + (pos >> 1)) >> 1;
                    float* o = (float*)outp;
                    o[((size_t)(b * 512 + oc)) * 256 + pout] = v;
                }
            }
        }
    }
}

// ---------------- launch ----------------
extern "C" void kernel_launch(void* const* d_in, const int* in_sizes, int n_in,
                              void* d_out, int out_size, void* d_ws, size_t ws_size,
                              hipStream_t stream) {
    const float* x  = (const float*)d_in[0];
    const float* w1 = (const float*)d_in[1];
    const float* b1 = (const float*)d_in[2];
    const float* g1 = (const float*)d_in[3];
    const float* be1 = (const float*)d_in[4];
    const float* m1 = (const float*)d_in[5];
    const float* v1 = (const float*)d_in[6];
    const float* w2 = (const float*)d_in[7];
    const float* b2 = (const float*)d_in[8];
    const float* g2 = (const float*)d_in[9];
    const float* be2 = (const float*)d_in[10];
    const float* m2 = (const float*)d_in[11];
    const float* v2 = (const float*)d_in[12];
    float* out = (float*)d_out;

    char* ws = (char*)d_ws;
    u16* gathered = (u16*)(ws);                    // 101,056,512 B
    u16* w1t      = (u16*)(ws + 101056512);        // 13,107,200 B
    u16* w2t      = (u16*)(ws + 114163712);        //  7,864,320 B
    float* bn1s   = (float*)(ws + 122028032);
    float* bn1t   = bn1s + 512;
    float* bn2s   = bn1s + 1024;
    float* bn2t   = bn1s + 1536;
    u16* pooled1  = (u16*)(ws + 122036224);        // 16,908,288 B

    prep_w1<<<25600, 256, 0, stream>>>(w1, w1t);
    prep_w2<<<15360, 256, 0, stream>>>(w2, w2t);
    prep_bn<<<2, 256, 0, stream>>>(g1, be1, m1, v1, bn1s, bn1t);
    prep_bn<<<2, 256, 0, stream>>>(g2, be2, m2, v2, bn2s, bn2t);
    zero_pads<<<128, 256, 0, stream>>>(gathered, pooled1);
    gather_topk<<<8192, 256, 0, stream>>>(x, gathered);

    // conv1+pool1: 256pos x 256oc tile; 2m x 4n waves, MF32=4, NF=2
    conv_fused<12, 3, 5, 5, 32, 32, 4, 2, 2, 2, 8, 1, 448, 12336, 64,
               true, false>
        <<<512, 512, 0, stream>>>(gathered, w1t, b1, bn1s, bn1t, pooled1);
    // conv2+pool2: 128pos x 128oc tile; 2m x 2n waves (4 waves), MF32=2, NF=2
    conv_fused<4, 1, 5, 3, 64, 8, 2, 1, 2, 4, 4, 3, 320, 2064, 32,
               false, true>
        <<<256, 256, 0, stream>>>(pooled1, w2t, b2, bn2s, bn2t, out);
}

// Round 14
// 773.523 us; speedup vs baseline: 1.0318x; 1.0318x over previous
//
#include <hip/hip_runtime.h>
#include <hip/hip_bf16.h>

typedef short bf16x8 __attribute__((ext_vector_type(8)));
typedef float f32x16 __attribute__((ext_vector_type(16)));
typedef unsigned short u16;

__device__ __forceinline__ u16 f2bf(float v) {
    union { __hip_bfloat16 h; u16 u; } cv;
    cv.h = __float2bfloat16(v);
    return cv.u;
}

__device__ __forceinline__ void gld_lds16(const u16* g, u16* l) {
    __builtin_amdgcn_global_load_lds(
        (const __attribute__((address_space(1))) void*)g,
        (__attribute__((address_space(3))) void*)l, 16, 0, 0);
}

// ---------------- prep kernels ----------------
// Wt layout: [T][ocs(8)][c(4)][ocl(64)][e(8)]  with T = (ic>>5)*TAPS + tap
__global__ void prep_w1(const float* __restrict__ w, u16* __restrict__ o) {
    int idx = blockIdx.x * 256 + threadIdx.x;
    if (idx >= 25 * 512 * 512) return;
    int e = idx & 7, ocl = (idx >> 3) & 63, c = (idx >> 9) & 3;
    int ocs = (idx >> 11) & 7, T = idx >> 14;
    int icb = T / 25, tap = T - icb * 25;
    int ic = icb * 32 + c * 8 + e;
    int oc = ocs * 64 + ocl;
    int kh = tap / 5, kw = tap - kh * 5;
    o[idx] = f2bf(w[(((size_t)oc * 512 + ic) * 5 + kh) * 5 + kw]);
}

__global__ void prep_w2(const float* __restrict__ w, u16* __restrict__ o) {
    int idx = blockIdx.x * 256 + threadIdx.x;
    if (idx >= 15 * 512 * 512) return;
    int e = idx & 7, ocl = (idx >> 3) & 63, c = (idx >> 9) & 3;
    int ocs = (idx >> 11) & 7, T = idx >> 14;
    int icb = T / 15, tap = T - icb * 15;
    int ic = icb * 32 + c * 8 + e;
    int oc = ocs * 64 + ocl;
    int kh = tap / 3, kw = tap - kh * 3;
    o[idx] = f2bf(w[(((size_t)oc * 512 + ic) * 5 + kh) * 3 + kw]);
}

__global__ void prep_bn(const float* __restrict__ g, const float* __restrict__ b,
                        const float* __restrict__ m, const float* __restrict__ v,
                        float* __restrict__ scale, float* __restrict__ shift) {
    int i = blockIdx.x * 256 + threadIdx.x;
    if (i >= 512) return;
    float s = g[i] * rsqrtf(v[i] + 1e-5f);
    scale[i] = s;
    shift[i] = b[i] - m[i] * s;
}

// zero pads: gathered [b][cc64][row 12336][8] rows h in {0,1,1026,1027} (x12 w)
//            pooled1  [b][cc64][row 2064][8] rows hp in {0,1,514,515} (x4 w)
__global__ void zero_pads(u16* __restrict__ gath, u16* __restrict__ pooled) {
    int idx = blockIdx.x * 256 + threadIdx.x;
    if (idx < 24576) {
        int w = idx % 12, r = idx / 12;
        int h4 = r & 3; r >>= 2;
        int cc = r & 63, b = r >> 6;
        int h = (h4 < 2) ? h4 : 1024 + h4;        // 0,1,1026,1027
        *(int4*)&gath[(((size_t)(b * 64 + cc)) * 12336 + h * 12 + w) * 8] =
            int4{0, 0, 0, 0};
    } else if (idx < 24576 + 8192) {
        int j = idx - 24576;
        int w = j & 3, r = j >> 2;
        int h4 = r & 3; r >>= 2;
        int cc = r & 63, b = r >> 6;
        int hp = (h4 < 2) ? h4 : 512 + h4;        // 0,1,514,515
        *(int4*)&pooled[(((size_t)(b * 64 + cc)) * 2064 + hp * 4 + w) * 8] =
            int4{0, 0, 0, 0};
    }
}

// ---------------- scores + top-k + gather ----------------
// writes gathered[b][cc(64)][row = (t+2)*12 + s][8 ic] bf16
__global__ __launch_bounds__(256) void gather_topk(const float* __restrict__ x,
                                                   u16* __restrict__ g) {
    int bt = blockIdx.x;
    int b = bt >> 10, t = bt & 1023;
    const float* xb = x + (size_t)b * 1024 * 512;
    const float* xt = xb + (size_t)t * 512;
    __shared__ float xts[512];
    __shared__ float sc[23];
    __shared__ int sel[12];
    int tid = threadIdx.x;
    for (int i = tid; i < 512; i += 256) xts[i] = xt[i];
    __syncthreads();
    int j0 = t - 11; if (j0 < 0) j0 = 0;
    int j1 = t + 11; if (j1 > 1023) j1 = 1023;
    int C = j1 - j0 + 1;                        // 12..23, always >= 12
    int wave = tid >> 6, lane = tid & 63;
    for (int c = wave; c < C; c += 4) {
        const float* xj = xb + (size_t)(j0 + c) * 512;
        double s = 0.0;
        #pragma unroll
        for (int e = 0; e < 8; ++e) {
            int d = lane * 8 + e;
            s += (double)xj[d] * (double)xts[d];
        }
        #pragma unroll
        for (int off = 32; off; off >>= 1) s += __shfl_xor(s, off, 64);
        if (lane == 0) sc[c] = (float)(s / 22.627416997969522);  // / sqrt(512)
    }
    __syncthreads();
    // wave-parallel top-12 select (stable: lower index wins ties)
    if (tid < 64) {
        bool selme = false;
        float v = (tid < C) ? sc[tid] : 0.f;
        if (tid < C) {
            int r = 0;
            #pragma unroll
            for (int k = 0; k < 23; ++k) {
                if (k < C) {
                    float u = sc[k];
                    r += (u > v) || (u == v && k < tid);
                }
            }
            selme = (r < 12);
        }
        unsigned long long m = __ballot(selme);
        if (selme) {
            int posn = __popcll(m & ((1ull << tid) - 1ull));
            sel[posn] = j0 + tid;               // ascending c == sorted ids
        }
    }
    __syncthreads();
    const size_t rowbase = (size_t)(t + 2) * 12;
    for (int i = tid; i < 768; i += 256) {           // 64 cc x 12 s blocks
        int cc = i / 12, s = i - cc * 12;
        const float* src = xb + (size_t)sel[s] * 512 + cc * 8;
        float4 f0 = *(const float4*)src;
        float4 f1 = *(const float4*)(src + 4);
        u16 pk[8] = {f2bf(f0.x), f2bf(f0.y), f2bf(f0.z), f2bf(f0.w),
                     f2bf(f1.x), f2bf(f1.y), f2bf(f1.z), f2bf(f1.w)};
        *(int4*)&g[(((size_t)(b * 64 + cc)) * 12336 + rowbase + s) * 8] =
            *(const int4*)pk;
    }
}

// ---------------- conv1 + bias + BN + ReLU + fused 2x2 pool ----------------
// EXACT round-10 codegen shape (scalar wE0..3/wO0..3, inline unrolled body),
// compiled as its OWN template so conv2's instantiation can't perturb
// register allocation (co-compilation sensitivity, rule #19).
template <int IN_W, int LOG_OW, int KH, int KW, int TH, int HTB, int MF32,
          int ARP, int PLANE, int CPX>
__global__ __launch_bounds__(512, 1) void conv1_fused(
    const u16* __restrict__ A, const u16* __restrict__ Wt,
    const float* __restrict__ bias, const float* __restrict__ bnsc,
    const float* __restrict__ bnsh, void* __restrict__ outp) {
    constexpr int OW = 1 << LOG_OW;
    constexpr int TAPS = KH * KW;
    constexpr int JC = ARP / 64;
    constexpr int MFR = (32 >> LOG_OW) * IN_W;   // A-row advance per mf
    constexpr int SLAB = ARP * 8 + 32;           // shorts; +64B pad per slab
    constexpr int NB = 2 * TAPS;                 // bodies per chunk (even)
    __shared__ u16 As_l[2][8 * SLAB];

    const int tid = threadIdx.x;
    const int bid = blockIdx.x;
    const int lb = (bid & 7) * CPX + (bid >> 3);   // XCD-chunked swizzle
    const int n0 = (lb & 1) * 256;
    const int mt = lb >> 1;
    const int b = mt / HTB;
    const int h0 = (mt % HTB) * TH;

    const int lane = tid & 63;
    const int wv = tid >> 6;
    const int wm = wv >> 2, wn = wv & 3;
    const int l31 = lane & 31, kgrp = lane >> 5;

    const int pos0 = wm * MF32 * 32 + l31;
    const int rowb0 = (pos0 >> LOG_OW) * IN_W + (pos0 & (OW - 1));
    const int aoffb = kgrp * SLAB + rowb0 * 8;

    const int ocs = (lb & 1) * 4 + wn;
    // per-lane W base (body T=0): [ocs][c = kgrp][ocl = l31][8]
    const u16* wlane = Wt + (size_t)ocs * 2048 + kgrp * 512 + l31 * 8;

    const u16* gAh = A + (((size_t)b * 64) * PLANE + h0 * IN_W + lane) * 8;

    f32x16 acc[MF32][2];
    #pragma unroll
    for (int i = 0; i < MF32; ++i)
        #pragma unroll
        for (int j = 0; j < 2; ++j)
            acc[i][j] = f32x16{0.f,0.f,0.f,0.f,0.f,0.f,0.f,0.f,
                               0.f,0.f,0.f,0.f,0.f,0.f,0.f,0.f};

    // prologue: A chunk 0 -> buf0 (DMA); W body 0 -> wE set
    #pragma unroll 1
    for (int q = wv; q < 8 * JC; q += 8) {
        int c8 = q / JC, j = q - c8 * JC;
        gld_lds16(gAh + ((size_t)(c8 * PLANE) + j * 64) * 8,
                  &As_l[0][c8 * SLAB + j * 512]);
    }
    bf16x8 wE0 = *(const bf16x8*)(wlane);
    bf16x8 wE1 = *(const bf16x8*)(wlane + 256);
    bf16x8 wE2 = *(const bf16x8*)(wlane + 1024);
    bf16x8 wE3 = *(const bf16x8*)(wlane + 1280);
    bf16x8 wO0, wO1, wO2, wO3;
    asm volatile("s_waitcnt vmcnt(0)" ::: "memory");
    __builtin_amdgcn_s_barrier();

    #pragma unroll 1
    for (int cn = 0; cn < 8; ++cn) {
        // stage chunk cn+1 into the other buffer (lands ~NB bodies later)
        if (cn < 7) {
            const int chn = cn + 1;
            #pragma unroll 1
            for (int q = wv; q < 8 * JC; q += 8) {
                int c8 = q / JC, j = q - c8 * JC;
                gld_lds16(gAh + ((size_t)((chn * 8 + c8) * PLANE) + j * 64) * 8,
                          &As_l[chn & 1][c8 * SLAB + j * 512]);
            }
        }
        const u16* aBufc = &As_l[cn & 1][0] + aoffb;
        const u16* wch = wlane + ((size_t)cn * NB + 1) * 16384;  // next-body W
        // chunk head: afA <- body 0 k0
        bf16x8 afA[MF32], afB[MF32];
        #pragma unroll
        for (int mf = 0; mf < MF32; ++mf)
            afA[mf] = *(const bf16x8*)(aBufc + MFR * mf * 8);
        #pragma unroll
        for (int bi = 0; bi < NB; ++bi) {
            const int gh = bi / TAPS, t = bi - gh * TAPS;
            const int kh_ = t / KW;
            const int toff = kh_ * IN_W + (t - kh_ * KW);
            const u16* aR = aBufc + gh * 4 * SLAB;
            const u16* wS = wch + (size_t)bi * 16384;   // prefetch body bi+1
            if (bi & 1) {
                wE0 = *(const bf16x8*)(wS);
                wE1 = *(const bf16x8*)(wS + 256);
                wE2 = *(const bf16x8*)(wS + 1024);
                wE3 = *(const bf16x8*)(wS + 1280);
            } else {
                wO0 = *(const bf16x8*)(wS);
                wO1 = *(const bf16x8*)(wS + 256);
                wO2 = *(const bf16x8*)(wS + 1024);
                wO3 = *(const bf16x8*)(wS + 1280);
            }
            // issue k1 frags for this body
            #pragma unroll
            for (int mf = 0; mf < MF32; ++mf)
                afB[mf] = *(const bf16x8*)(aR + (toff + MFR * mf) * 8 + 2 * SLAB);
            __builtin_amdgcn_s_setprio(1);
            #pragma unroll
            for (int mf = 0; mf < MF32; ++mf) {
                acc[mf][0] = __builtin_amdgcn_mfma_f32_32x32x16_bf16(
                    afA[mf], (bi & 1) ? wO0 : wE0, acc[mf][0], 0, 0, 0);
                acc[mf][1] = __builtin_amdgcn_mfma_f32_32x32x16_bf16(
                    afA[mf], (bi & 1) ? wO1 : wE1, acc[mf][1], 0, 0, 0);
            }
            __builtin_amdgcn_s_setprio(0);
            // issue next body's k0 frags
            if (bi + 1 < NB) {
                const int bn2 = bi + 1;
                const int ghn = bn2 / TAPS, tn = bn2 - ghn * TAPS;
                const int khn = tn / KW;
                const int toffn = khn * IN_W + (tn - khn * KW);
                const u16* aRn = aBufc + ghn * 4 * SLAB;
                #pragma unroll
                for (int mf = 0; mf < MF32; ++mf)
                    afA[mf] = *(const bf16x8*)(aRn + (toffn + MFR * mf) * 8);
            }
            __builtin_amdgcn_s_setprio(1);
            #pragma unroll
            for (int mf = 0; mf < MF32; ++mf) {
                acc[mf][0] = __builtin_amdgcn_mfma_f32_32x32x16_bf16(
                    afB[mf], (bi & 1) ? wO2 : wE2, acc[mf][0], 0, 0, 0);
                acc[mf][1] = __builtin_amdgcn_mfma_f32_32x32x16_bf16(
                    afB[mf], (bi & 1) ? wO3 : wE3, acc[mf][1], 0, 0, 0);
            }
            __builtin_amdgcn_s_setprio(0);
        }
        // chunk end: own A-DMAs are older than the in-flight W loads
        asm volatile("s_waitcnt vmcnt(4)" ::: "memory");
        __builtin_amdgcn_s_barrier();
    }
    asm volatile("s_waitcnt vmcnt(0)" ::: "memory");

    // epilogue: y = relu(max4(conv)*sc + (bias*sc + sh)), fused 2x2 pool.
    // C/D 32x32: col = lane&31, row = (r&3) + 8*(r>>2) + 4*(lane>>5)
    #pragma unroll
    for (int nf = 0; nf < 2; ++nf) {
        const int oc = n0 + wn * 64 + nf * 32 + l31;
        const float scv = bnsc[oc], shv = bnsh[oc], bi2 = bias[oc];
        const float shh = fmaf(bi2, scv, shv);
        #pragma unroll
        for (int mf = 0; mf < MF32; ++mf) {
            #pragma unroll
            for (int q = 0; q < 4; ++q) {
                // quad {r0,r0+1,r0+4,r0+5}: w-pair (+1 row) x h-pair (+8)
                const int r0 = (q & 1) * 2 + (q >> 1) * 8;   // 0,2,8,10
                float mx = fmaxf(
                    fmaxf(acc[mf][nf][r0], acc[mf][nf][r0 + 1]),
                    fmaxf(acc[mf][nf][r0 + 4], acc[mf][nf][r0 + 5]));
                float v = fmaxf(fmaf(mx, scv, shh), 0.f);
                const int row0 = (r0 & 3) + 8 * (r0 >> 2) + 4 * kgrp;
                const int pos = wm * MF32 * 32 + mf * 32 + row0;
                const int h = h0 + (pos >> LOG_OW);
                const int w = pos & (OW - 1);
                const int prow = (2 + (h >> 1)) * 4 + (w >> 1);
                u16* o = (u16*)outp;
                o[(((size_t)(b * 64 + (oc >> 3))) * 2064 + prow) * 8 +
                  (oc & 7)] = f2bf(v);
            }
        }
    }
}

// ---------------- conv2 + bias + BN + ReLU + fused 2x2 pool -> d_out -------
// 4-wave (2m x 2n) 128pos x 128oc tile, single-buffer A, 3 blocks/CU.
#define STAGEA2(CH) do {                                                      \
    _Pragma("unroll 1")                                                       \
    for (int q_ = wv; q_ < 8 * JC; q_ += 4) {                                 \
        int c8_ = q_ / JC, j_ = q_ - c8_ * JC;                                \
        const u16* p_ = gAh +                                                 \
            ((size_t)(((CH) * 8 + c8_) * PLANE) + j_ * 64) * 8;               \
        if (p_ > gAmax) p_ = gAmax;                                           \
        gld_lds16(p_, &As_l[c8_ * SLAB + j_ * 512]);                          \
    }                                                                         \
  } while (0)

#define CBODY2(BI, WUSE, WPRE) do {                                           \
    const int gh_ = (BI) / TAPS, t_ = (BI) - gh_ * TAPS;                      \
    const int kh2_ = t_ / KW;                                                 \
    const int toff_ = kh2_ * IN_W + (t_ - kh2_ * KW);                         \
    const u16* aR_ = aBufc + gh_ * 4 * SLAB;                                  \
    const u16* wS_ = wch + (size_t)(BI) * 16384;                              \
    WPRE[0] = *(const bf16x8*)(wS_);                                          \
    WPRE[1] = *(const bf16x8*)(wS_ + 256);                                    \
    WPRE[2] = *(const bf16x8*)(wS_ + 1024);                                   \
    WPRE[3] = *(const bf16x8*)(wS_ + 1280);                                   \
    _Pragma("unroll")                                                         \
    for (int mf = 0; mf < MF32; ++mf)                                         \
        afB[mf] = *(const bf16x8*)(aR_ + (toff_ + MFR * mf) * 8 + 2 * SLAB);  \
    __builtin_amdgcn_s_setprio(1);                                            \
    _Pragma("unroll")                                                         \
    for (int mf = 0; mf < MF32; ++mf)                                         \
        _Pragma("unroll")                                                     \
        for (int nf = 0; nf < 2; ++nf)                                        \
            acc[mf][nf] = __builtin_amdgcn_mfma_f32_32x32x16_bf16(            \
                afA[mf], WUSE[nf], acc[mf][nf], 0, 0, 0);                     \
    __builtin_amdgcn_s_setprio(0);                                            \
    if ((BI) + 1 < NB) {                                                      \
        const int bn2_ = (BI) + 1;                                            \
        const int ghn_ = bn2_ / TAPS, tn_ = bn2_ - ghn_ * TAPS;               \
        const int khn_ = tn_ / KW;                                            \
        const int toffn_ = khn_ * IN_W + (tn_ - khn_ * KW);                   \
        const u16* aRn_ = aBufc + ghn_ * 4 * SLAB;                            \
        _Pragma("unroll")                                                     \
        for (int mf = 0; mf < MF32; ++mf)                                     \
            afA[mf] = *(const bf16x8*)(aRn_ + (toffn_ + MFR * mf) * 8);       \
    }                                                                         \
    __builtin_amdgcn_s_setprio(1);                                            \
    _Pragma("unroll")                                                         \
    for (int mf = 0; mf < MF32; ++mf)                                         \
        _Pragma("unroll")                                                     \
        for (int nf = 0; nf < 2; ++nf)                                        \
            acc[mf][nf] = __builtin_amdgcn_mfma_f32_32x32x16_bf16(            \
                afB[mf], WUSE[2 + nf], acc[mf][nf], 0, 0, 0);                 \
    __builtin_amdgcn_s_setprio(0);                                            \
  } while (0)

template <int IN_W, int LOG_OW, int KH, int KW, int TH, int HTB, int MF32,
          int NTILES, int ARP, int PLANE, int CPX>
__global__ __launch_bounds__(256, 3) void conv2_fused(
    const u16* __restrict__ A, const u16* __restrict__ Wt,
    const float* __restrict__ bias, const float* __restrict__ bnsc,
    const float* __restrict__ bnsh, float* __restrict__ outp) {
    constexpr int OW = 1 << LOG_OW;
    constexpr int TAPS = KH * KW;
    constexpr int JC = ARP / 64;
    constexpr int MFR = (32 >> LOG_OW) * IN_W;
    constexpr int SLAB = ARP * 8 + 32;
    constexpr int NB = 2 * TAPS;
    __shared__ u16 As_l[8 * SLAB];

    const int tid = threadIdx.x;
    const int bid = blockIdx.x;
    const int lb = (bid & 7) * CPX + (bid >> 3);
    const int n0 = (lb % NTILES) * (512 / NTILES);
    const int mt = lb / NTILES;
    const int b = mt / HTB;
    const int h0 = (mt % HTB) * TH;

    const int lane = tid & 63;
    const int wv = tid >> 6;
    const int wn = wv & 1;
    const int wm = wv >> 1;
    const int l31 = lane & 31, kgrp = lane >> 5;

    const int pos0 = wm * MF32 * 32 + l31;
    const int rowb0 = (pos0 >> LOG_OW) * IN_W + (pos0 & (OW - 1));
    const int aoffb = kgrp * SLAB + rowb0 * 8;

    const int ocs_base = (lb % NTILES) * (8 / NTILES);
    const u16* wlane = Wt + (size_t)(ocs_base + wn) * 2048
                       + kgrp * 512 + l31 * 8;

    const u16* gAh = A + (((size_t)b * 64) * PLANE + h0 * IN_W + lane) * 8;
    const u16* gAmax = A + (size_t)512 * PLANE * 8 - 8;

    f32x16 acc[MF32][2];
    #pragma unroll
    for (int i = 0; i < MF32; ++i)
        #pragma unroll
        for (int j = 0; j < 2; ++j)
            acc[i][j] = f32x16{0.f,0.f,0.f,0.f,0.f,0.f,0.f,0.f,
                               0.f,0.f,0.f,0.f,0.f,0.f,0.f,0.f};

    STAGEA2(0);
    bf16x8 wE[4], wO[4];
    wE[0] = *(const bf16x8*)(wlane);
    wE[1] = *(const bf16x8*)(wlane + 256);
    wE[2] = *(const bf16x8*)(wlane + 1024);
    wE[3] = *(const bf16x8*)(wlane + 1280);
    asm volatile("s_waitcnt vmcnt(0)" ::: "memory");
    __builtin_amdgcn_s_barrier();

    const u16* wch = wlane + 16384;
    #pragma unroll 1
    for (int cn = 0; cn < 8; ++cn) {
        const u16* aBufc = &As_l[0] + aoffb;
        bf16x8 afA[MF32], afB[MF32];
        #pragma unroll
        for (int mf = 0; mf < MF32; ++mf)
            afA[mf] = *(const bf16x8*)(aBufc + MFR * mf * 8);
        #pragma unroll
        for (int bi = 0; bi < NB; ++bi) {
            if ((bi & 1) == 0) CBODY2(bi, wE, wO);
            else              CBODY2(bi, wO, wE);
        }
        wch += (size_t)NB * 16384;
        if (cn < 7) {
            __builtin_amdgcn_s_barrier();
            STAGEA2(cn + 1);
            asm volatile("s_waitcnt vmcnt(0)" ::: "memory");
            __builtin_amdgcn_s_barrier();
        }
    }
    asm volatile("s_waitcnt vmcnt(0)" ::: "memory");

    // epilogue: fused pool2 -> d_out fp32 [8][512][256]
    #pragma unroll
    for (int nf = 0; nf < 2; ++nf) {
        const int oc = n0 + wn * 64 + nf * 32 + l31;
        const float scv = bnsc[oc], shv = bnsh[oc], bi2 = bias[oc];
        const float shh = fmaf(bi2, scv, shv);
        #pragma unroll
        for (int mf = 0; mf < MF32; ++mf) {
            #pragma unroll
            for (int q = 0; q < 4; ++q) {
                const int r0 = q * 4;
                float mx = fmaxf(
                    fmaxf(acc[mf][nf][r0], acc[mf][nf][r0 + 1]),
                    fmaxf(acc[mf][nf][r0 + 2], acc[mf][nf][r0 + 3]));
                float v = fmaxf(fmaf(mx, scv, shh), 0.f);
                const int row0 = 8 * (r0 >> 2) + 4 * kgrp;
                const int pos = wm * MF32 * 32 + mf * 32 + row0;
                const int pout = (h0 + (pos >> 1)) >> 1;
                outp[((size_t)(b * 512 + oc)) * 256 + pout] = v;
            }
        }
    }
}

// ---------------- launch ----------------
extern "C" void kernel_launch(void* const* d_in, const int* in_sizes, int n_in,
                              void* d_out, int out_size, void* d_ws, size_t ws_size,
                              hipStream_t stream) {
    const float* x  = (const float*)d_in[0];
    const float* w1 = (const float*)d_in[1];
    const float* b1 = (const float*)d_in[2];
    const float* g1 = (const float*)d_in[3];
    const float* be1 = (const float*)d_in[4];
    const float* m1 = (const float*)d_in[5];
    const float* v1 = (const float*)d_in[6];
    const float* w2 = (const float*)d_in[7];
    const float* b2 = (const float*)d_in[8];
    const float* g2 = (const float*)d_in[9];
    const float* be2 = (const float*)d_in[10];
    const float* m2 = (const float*)d_in[11];
    const float* v2 = (const float*)d_in[12];
    float* out = (float*)d_out;

    char* ws = (char*)d_ws;
    u16* gathered = (u16*)(ws);                    // 101,056,512 B
    u16* w1t      = (u16*)(ws + 101056512);        // 13,107,200 B
    u16* w2t      = (u16*)(ws + 114163712);        //  7,864,320 B
    float* bn1s   = (float*)(ws + 122028032);
    float* bn1t   = bn1s + 512;
    float* bn2s   = bn1s + 1024;
    float* bn2t   = bn1s + 1536;
    u16* pooled1  = (u16*)(ws + 122036224);        // 16,908,288 B

    prep_w1<<<25600, 256, 0, stream>>>(w1, w1t);
    prep_w2<<<15360, 256, 0, stream>>>(w2, w2t);
    prep_bn<<<2, 256, 0, stream>>>(g1, be1, m1, v1, bn1s, bn1t);
    prep_bn<<<2, 256, 0, stream>>>(g2, be2, m2, v2, bn2s, bn2t);
    zero_pads<<<128, 256, 0, stream>>>(gathered, pooled1);
    gather_topk<<<8192, 256, 0, stream>>>(x, gathered);

    // conv1+pool1: 256pos x 256oc tile; 2m x 4n waves, MF32=4 (r10 verbatim)
    conv1_fused<12, 3, 5, 5, 32, 32, 4, 448, 12336, 64>
        <<<512, 512, 0, stream>>>(gathered, w1t, b1, bn1s, bn1t, pooled1);
    // conv2+pool2: 128pos x 128oc tile; 2m x 2n waves, MF32=2
    conv2_fused<4, 1, 5, 3, 64, 8, 2, 4, 320, 2064, 32>
        <<<256, 256, 0, stream>>>(pooled1, w2t, b2, bn2s, bn2t, out);
}